// Round 19
// baseline (241.186 us; speedup 1.0000x reference)
//
#include <hip/hip_runtime.h>

typedef __bf16 bf16x8 __attribute__((ext_vector_type(8)));
typedef float f32x4 __attribute__((ext_vector_type(4)));

__device__ __forceinline__ float bf2f(unsigned short u) {
  return __uint_as_float(((unsigned)u) << 16);
}
__device__ __forceinline__ unsigned short f2bf(float f) {
  unsigned u = __float_as_uint(f);
  return (unsigned short)((u + 0x7fffu + ((u >> 16) & 1u)) >> 16);
}
__device__ __forceinline__ unsigned pack2(float a, float b) {
  return (unsigned)f2bf(a) | ((unsigned)f2bf(b) << 16);
}

// XOR swizzle on 16B blocks within a 128B row (T2 / Guideline 4).
#define SWZB(row, byte) ((byte) ^ (((row) & 7) << 4))

#define AS_GLOBAL(p) ((const __attribute__((address_space(1))) void*)(p))
#define AS_LDS(p) ((__attribute__((address_space(3))) void*)(p))

// ---------------- pre: 4x fp32->bf16 cvt + lambda scalar (grid.y==4) ----------------
__global__ __launch_bounds__(256) void pre_kernel(
    const float* __restrict__ s0, const float* __restrict__ s1,
    const float* __restrict__ s2, const float* __restrict__ s3,
    unsigned short* __restrict__ d0, unsigned short* __restrict__ d1,
    unsigned short* __restrict__ d2, unsigned short* __restrict__ d3,
    const float* __restrict__ lq1, const float* __restrict__ lq2,
    const float* __restrict__ lk1, const float* __restrict__ lk2,
    float* __restrict__ lamb, int n4) {
  if (blockIdx.y == 4) {
    if (blockIdx.x == 0 && threadIdx.x < 64) {
      int l = threadIdx.x;
      float p1 = lq1[l] * lk1[l];
      float p2 = lq2[l] * lk2[l];
      #pragma unroll
      for (int off = 32; off; off >>= 1) {
        p1 += __shfl_xor(p1, off);
        p2 += __shfl_xor(p2, off);
      }
      if (l == 0) lamb[0] = expf(p1) - expf(p2) + 0.7836057665316245f;  // LAMBDA_INIT
    }
    return;
  }
  int idx = blockIdx.x * 256 + threadIdx.x;
  if (idx >= n4) return;
  const float* s;
  unsigned short* d;
  switch (blockIdx.y) {
    case 0: s = s0; d = d0; break;
    case 1: s = s1; d = d1; break;
    case 2: s = s2; d = d2; break;
    default: s = s3; d = d3; break;
  }
  float4 v = reinterpret_cast<const float4*>(s)[idx];
  uint2 pk;
  pk.x = pack2(v.x, v.y);
  pk.y = pack2(v.z, v.w);
  reinterpret_cast<uint2*>(d)[idx] = pk;
}

// ---------------- GEMM (bf16 x bf16), BK=64, swizzled global_load_lds ----------------
// Single-buffer 1-phase: 32 KB LDS -> 3 blocks/CU; inter-block wave overlap (m114)
// hides the stage drain better than intra-block dbuf (R13 A/B: dbuf 64KB = 2 blocks/CU
// regressed 63->78 us). PLAIN store epilogue only (R11 lesson: fused sincos/scatter
// epilogue = scratch storm). NO setprio (m190: null-to-negative on lockstep waves).
template <typename OT>
__global__ __launch_bounds__(256)
void gemm_bk64(const unsigned short* __restrict__ A, const unsigned short* __restrict__ Bw,
               OT* __restrict__ C, int M, int K, int ldc) {
  __shared__ __align__(16) unsigned short As[128 * 64];
  __shared__ __align__(16) unsigned short Bs[128 * 64];
  const int tid = threadIdx.x;
  const int bm = blockIdx.x * 128, bn = blockIdx.y * 128;
  const int lane = tid & 63, wave = tid >> 6;
  const int wm = (wave >> 1) * 64, wn = (wave & 1) * 64;
  const int rr = lane & 15, lg = lane >> 4;
  const int srow = lane >> 3;           // row within 8-row slab
  const int sblk = (lane & 7) ^ srow;   // pre-swizzled 16B block
  const char* ab = reinterpret_cast<const char*>(As);
  const char* bb = reinterpret_cast<const char*>(Bs);
  OT* Cb = C + (size_t)(bn / ldc) * ((size_t)M * ldc) + (bn % ldc);
  f32x4 acc[4][4] = {};
  for (int kt = 0; kt < K; kt += 64) {
    __syncthreads();
    #pragma unroll
    for (int j = 0; j < 4; ++j) {
      int s = wave + j * 4;  // slab 0..15 (8 rows x 128 B each)
      const unsigned short* asrc = &A[(long)(bm + s * 8 + srow) * K + kt + sblk * 8];
      __builtin_amdgcn_global_load_lds(AS_GLOBAL(asrc), AS_LDS(&As[s * 512]), 16, 0, 0);
      const unsigned short* bsrc = &Bw[(long)(bn + s * 8 + srow) * K + kt + sblk * 8];
      __builtin_amdgcn_global_load_lds(AS_GLOBAL(bsrc), AS_LDS(&Bs[s * 512]), 16, 0, 0);
    }
    __syncthreads();  // vmcnt(0) drain
    bf16x8 af[4][2], bq[4][2];
    #pragma unroll
    for (int i = 0; i < 4; ++i) {
      int row = wm + i * 16 + rr;
      af[i][0] = *reinterpret_cast<const bf16x8*>(ab + row * 128 + SWZB(row, lg * 16));
      af[i][1] = *reinterpret_cast<const bf16x8*>(ab + row * 128 + SWZB(row, 64 + lg * 16));
    }
    #pragma unroll
    for (int j = 0; j < 4; ++j) {
      int row = wn + j * 16 + rr;
      bq[j][0] = *reinterpret_cast<const bf16x8*>(bb + row * 128 + SWZB(row, lg * 16));
      bq[j][1] = *reinterpret_cast<const bf16x8*>(bb + row * 128 + SWZB(row, 64 + lg * 16));
    }
    #pragma unroll
    for (int i = 0; i < 4; ++i)
      #pragma unroll
      for (int j = 0; j < 4; ++j) {
        acc[i][j] = __builtin_amdgcn_mfma_f32_16x16x32_bf16(af[i][0], bq[j][0], acc[i][j], 0, 0, 0);
        acc[i][j] = __builtin_amdgcn_mfma_f32_16x16x32_bf16(af[i][1], bq[j][1], acc[i][j], 0, 0, 0);
      }
  }
  const int cc = lane & 15;
  #pragma unroll
  for (int i = 0; i < 4; ++i)
    #pragma unroll
    for (int j = 0; j < 4; ++j)
      #pragma unroll
      for (int r = 0; r < 4; ++r) {
        long row = bm + wm + i * 16 + lg * 4 + r;
        long col = wn + j * 16 + cc;
        float v = acc[i][j][r];
        if constexpr (sizeof(OT) == 2) Cb[row * ldc + col] = f2bf(v);
        else                           Cb[row * ldc + col] = v;
      }
}

// ---------------- mid: rope(q) + rope(k,rel) + cvt(wo) + transpose(V), one launch ------
// All four depend only on QKV output + inputs; mutually independent -> flat partition.
#define ROPE_BLKS 8192
#define CVT_BLKS 4096
#define TRN_BLKS 1024
__global__ __launch_bounds__(256) void mid_kernel(
    const unsigned short* __restrict__ qraw, const unsigned short* __restrict__ kraw,
    const unsigned short* __restrict__ vraw, const float* __restrict__ rel,
    const float* __restrict__ wo,
    unsigned short* __restrict__ qatt, unsigned short* __restrict__ katt,
    unsigned short* __restrict__ wob, unsigned short* __restrict__ vtb) {
  __shared__ unsigned short ls[64][68];
  const int bid = blockIdx.x;
  const int tid = threadIdx.x;
  if (bid < 2 * ROPE_BLKS) {
    // RoPE (+rel_pos for k), with (b,t,hp,d)->(b,hp,t,d) transpose
    const int use_rel = bid >= ROPE_BLKS;
    const unsigned short* raw = use_rel ? kraw : qraw;
    unsigned short* outp = use_rel ? katt : qatt;
    int idx = (bid & (ROPE_BLKS - 1)) * 256 + tid;
    int i = idx & 31;
    int t = (idx >> 5) & 1023;
    int hp = (idx >> 15) & 31;
    int b = idx >> 20;
    int src = (b * 1024 + t) * 2048 + hp * 64 + 2 * i;
    unsigned pair = *reinterpret_cast<const unsigned*>(&raw[src]);
    float x1 = __uint_as_float(pair << 16);
    float x2 = __uint_as_float(pair & 0xffff0000u);
    if (use_rel) {
      x1 *= rel[t * 64 + 2 * i];
      x2 *= rel[t * 64 + 2 * i + 1];
    }
    float inv = expf(-0.28782313662425574f * (float)i);  // 10000^(-2i/64)
    float s, c;
    sincosf((float)t * inv, &s, &c);
    int dst = ((b * 32 + hp) * 1024 + t) * 64 + 2 * i;
    *reinterpret_cast<unsigned*>(&outp[dst]) = pack2(x1 * c - x2 * s, x1 * s + x2 * c);
  } else if (bid < 2 * ROPE_BLKS + CVT_BLKS) {
    // wo fp32 -> bf16
    int idx = (bid - 2 * ROPE_BLKS) * 256 + tid;
    float4 v = reinterpret_cast<const float4*>(wo)[idx];
    uint2 pk;
    pk.x = pack2(v.x, v.y);
    pk.y = pack2(v.z, v.w);
    reinterpret_cast<uint2*>(wob)[idx] = pk;
  } else {
    // V transpose: (b,t,2048) -> (b,n,1024)
    int tb = bid - (2 * ROPE_BLKS + CVT_BLKS);
    const int t0 = (tb & 15) * 64, n0 = ((tb >> 4) & 31) * 64, b = tb >> 9;
    #pragma unroll
    for (int p = 0; p < 4; ++p) {
      int idx = p * 256 + tid;
      int tl = idx >> 4, nq = (idx & 15) * 4;
      *reinterpret_cast<uint2*>(&ls[tl][nq]) = *reinterpret_cast<const uint2*>(
          &vraw[((long)(b * 1024 + t0 + tl)) * 2048 + n0 + nq]);
    }
    __syncthreads();
    #pragma unroll
    for (int p = 0; p < 4; ++p) {
      int idx = p * 256 + tid;
      int nl = idx >> 4, tq = (idx & 15) * 4;
      uint2 o;
      o.x = (unsigned)ls[tq + 0][nl] | ((unsigned)ls[tq + 1][nl] << 16);
      o.y = (unsigned)ls[tq + 2][nl] | ((unsigned)ls[tq + 3][nl] << 16);
      *reinterpret_cast<uint2*>(&vtb[((long)(b * 2048 + n0 + nl)) * 1024 + t0 + tq]) = o;
    }
  }
}

// ---------------- MFMA differential flash attention + fused sub-LN ----------------
// Balanced 2-pass blocks, T1 XCD decode. R18: NO K/V LDS staging at all - fragments
// load DIRECTLY from global (Common-mistake #7: K/V is 512KB/group, L2-resident via
// T1; a wave's frag load rows0-15 x 64B = contiguous 1KB = fully-coalesced L2 hits).
// Tile loop is BARRIER-FREE (waves independent; R15 vs R18 A/B showed stage-drain
// wasn't the cost - lockstep was). LDS = P (8KB, wave-private) + combine (16KB).
__global__ __launch_bounds__(256) void attn_mfma(
    const unsigned short* __restrict__ Qa,   // (B,32,T,64) bf16
    const unsigned short* __restrict__ Ka,   // (B,32,T,64) bf16
    const unsigned short* __restrict__ Vt,   // (B,2048,T) bf16 (V transposed)
    const float* __restrict__ lam_p,
    const float* __restrict__ subln,         // 128
    unsigned short* __restrict__ O) {        // (B,T,2048) bf16
  const int n = blockIdx.x;
  const int c = n & 7, m = n >> 3;
  const int g = c * 4 + (m >> 4);  // 0..31
  const int bx = m & 15;
  const int h = g & 15, b = g >> 4;

  const int tid = threadIdx.x;
  const int lane = tid & 63, w = tid >> 6;
  const int lg = lane >> 4, cc = lane & 15;
  const int hh = w >> 1, qoff = (w & 1) * 16;

  __shared__ __align__(16) unsigned short PbBuf[4 * 16 * 64];  // 8 KB, per-wave P
  __shared__ __align__(16) float CbBuf[32 * 128];              // 16 KB, combine scratch

  const float lam = lam_p[0];
  char* pbb = reinterpret_cast<char*>(PbBuf) + w * 2048;
  float* cb = CbBuf;

  float sl[8];
  #pragma unroll
  for (int jc = 0; jc < 8; ++jc) sl[jc] = subln[jc * 16 + cc];

  const long kbase = (long)((b * 32 + 2 * h + hh) * 1024);
  const unsigned short* Kg = &Ka[kbase * 64];                       // this sub-head's K
  const unsigned short* Vg = &Vt[((long)(b * 2048 + h * 128)) * 1024];  // head's V^T

  for (int pass = 0; pass < 2; ++pass) {
    const int q0 = (pass ? (31 - bx) : bx) * 32;
    const int nt = ((q0 + 31) >> 6) + 1;

    bf16x8 qf[2];
    {
      const long qrow = q0 + qoff + cc;
      #pragma unroll
      for (int c2 = 0; c2 < 2; ++c2)
        qf[c2] = *reinterpret_cast<const bf16x8*>(&Qa[(kbase + qrow) * 64 + c2 * 32 + lg * 8]);
    }
    f32x4 acc_o[8];
    float mS[4], lS[4];
    #pragma unroll
    for (int jc = 0; jc < 8; ++jc) acc_o[jc] = (f32x4){0.f, 0.f, 0.f, 0.f};
    #pragma unroll
    for (int r = 0; r < 4; ++r) { mS[r] = -1e30f; lS[r] = 0.f; }

    for (int tile = 0; tile < nt; ++tile) {
      const int k0 = tile * 64;

      // ---- QK^T (K frags direct from global; wave-aggregate fully coalesced) ----
      f32x4 s4[4];
      #pragma unroll
      for (int j = 0; j < 4; ++j) s4[j] = (f32x4){0.f, 0.f, 0.f, 0.f};
      #pragma unroll
      for (int j = 0; j < 4; ++j) {
        int row = k0 + j * 16 + cc;
        const unsigned short* kr = &Kg[(long)row * 64 + lg * 8];
        bf16x8 kb0 = *reinterpret_cast<const bf16x8*>(kr);
        bf16x8 kb1 = *reinterpret_cast<const bf16x8*>(kr + 32);
        s4[j] = __builtin_amdgcn_mfma_f32_16x16x32_bf16(qf[0], kb0, s4[j], 0, 0, 0);
        s4[j] = __builtin_amdgcn_mfma_f32_16x16x32_bf16(qf[1], kb1, s4[j], 0, 0, 0);
      }
      // scale + causal mask
      #pragma unroll
      for (int j = 0; j < 4; ++j) {
        int kcol = k0 + j * 16 + cc;
        #pragma unroll
        for (int r = 0; r < 4; ++r) {
          int qrow = q0 + qoff + lg * 4 + r;
          float s = s4[j][r] * 0.125f;
          s4[j][r] = (kcol > qrow) ? -1e30f : s;
        }
      }
      // online softmax (row-reduce over 16-lane col group)
      float rescv[4];
      #pragma unroll
      for (int r = 0; r < 4; ++r) {
        float mx = fmaxf(fmaxf(s4[0][r], s4[1][r]), fmaxf(s4[2][r], s4[3][r]));
        mx = fmaxf(mx, __shfl_xor(mx, 1));
        mx = fmaxf(mx, __shfl_xor(mx, 2));
        mx = fmaxf(mx, __shfl_xor(mx, 4));
        mx = fmaxf(mx, __shfl_xor(mx, 8));
        float mold = mS[r];
        float mnew = fmaxf(mold, mx);
        mS[r] = mnew;
        float rsc = __expf(mold - mnew);
        rescv[r] = rsc;
        float ls = 0.f;
        #pragma unroll
        for (int j = 0; j < 4; ++j) {
          float p = __expf(s4[j][r] - mnew);  // masked -> 0
          s4[j][r] = p;
          ls += p;
        }
        ls += __shfl_xor(ls, 1);
        ls += __shfl_xor(ls, 2);
        ls += __shfl_xor(ls, 4);
        ls += __shfl_xor(ls, 8);
        lS[r] = lS[r] * rsc + ls;
      }
      // write P (bf16) into wave-private swizzled buffer (no barrier needed)
      #pragma unroll
      for (int j = 0; j < 4; ++j)
        #pragma unroll
        for (int r = 0; r < 4; ++r) {
          int rowl = lg * 4 + r;
          *reinterpret_cast<unsigned short*>(
              pbb + rowl * 128 + SWZB(rowl, (j * 16 + cc) * 2)) = f2bf(s4[j][r]);
        }

      // ---- PV (V^T frags direct from global) ----
      bf16x8 pa[2];
      #pragma unroll
      for (int c2 = 0; c2 < 2; ++c2)
        pa[c2] = *reinterpret_cast<const bf16x8*>(pbb + cc * 128 + SWZB(cc, lg * 16 + c2 * 64));
      #pragma unroll
      for (int jc = 0; jc < 8; ++jc)
        #pragma unroll
        for (int r = 0; r < 4; ++r)
          acc_o[jc][r] *= rescv[r];
      #pragma unroll
      for (int jc = 0; jc < 8; ++jc) {
        int row = jc * 16 + cc;
        const unsigned short* vr = &Vg[(long)row * 1024 + k0 + lg * 8];
        bf16x8 vf0 = *reinterpret_cast<const bf16x8*>(vr);
        bf16x8 vf1 = *reinterpret_cast<const bf16x8*>(vr + 32);
        acc_o[jc] = __builtin_amdgcn_mfma_f32_16x16x32_bf16(pa[0], vf0, acc_o[jc], 0, 0, 0);
        acc_o[jc] = __builtin_amdgcn_mfma_f32_16x16x32_bf16(pa[1], vf1, acc_o[jc], 0, 0, 0);
      }
    }

    // ---- pass epilogue: cross-wave diff combine + RMS + subln + store ----
    __syncthreads();  // prev pass's cb reads done (and wave sync before exchange)
    if (hh == 1) {
      #pragma unroll
      for (int r = 0; r < 4; ++r) {
        float inv2 = lam / lS[r];
        int row = qoff + lg * 4 + r;
        #pragma unroll
        for (int jc = 0; jc < 8; ++jc)
          cb[row * 128 + ((jc ^ (row & 7)) * 16 + cc)] = acc_o[jc][r] * inv2;
      }
    }
    __syncthreads();
    if (hh == 0) {
      float sc[4];
      #pragma unroll
      for (int r = 0; r < 4; ++r) {
        float inv1 = 1.f / lS[r];
        int row = qoff + lg * 4 + r;
        float ss = 0.f;
        #pragma unroll
        for (int jc = 0; jc < 8; ++jc) {
          float at = acc_o[jc][r] * inv1 - cb[row * 128 + ((jc ^ (row & 7)) * 16 + cc)];
          acc_o[jc][r] = at;
          ss += at * at;
        }
        ss += __shfl_xor(ss, 1);
        ss += __shfl_xor(ss, 2);
        ss += __shfl_xor(ss, 4);
        ss += __shfl_xor(ss, 8);
        sc[r] = rsqrtf(ss * (1.f / 128.f) + 1e-5f);
      }
      #pragma unroll
      for (int r = 0; r < 4; ++r) {
        long qrow = q0 + qoff + lg * 4 + r;
        #pragma unroll
        for (int jc = 0; jc < 8; ++jc) {
          O[(long)(b * 1024 + qrow) * 2048 + h * 128 + jc * 16 + cc] =
              f2bf(acc_o[jc][r] * sc[r] * sl[jc]);
        }
      }
    }
  }
}

extern "C" void kernel_launch(void* const* d_in, const int* in_sizes, int n_in,
                              void* d_out, int out_size, void* d_ws, size_t ws_size,
                              hipStream_t stream) {
  (void)in_sizes; (void)n_in; (void)out_size; (void)ws_size;
  const float* x    = (const float*)d_in[0];
  const float* rel  = (const float*)d_in[1];
  const float* wq   = (const float*)d_in[2];
  const float* wk   = (const float*)d_in[3];
  const float* wv   = (const float*)d_in[4];
  const float* lq1  = (const float*)d_in[5];
  const float* lq2  = (const float*)d_in[6];
  const float* lk1  = (const float*)d_in[7];
  const float* lk2  = (const float*)d_in[8];
  const float* subw = (const float*)d_in[9];
  const float* wo   = (const float*)d_in[10];
  float* out = (float*)d_out;

  char* ws = (char*)d_ws;
  const size_t SZ = (size_t)2048 * 2048 * 2;  // 8 MB
  // Liveness-ordered layout (56 MB + 4 B):
  //   [0..3SZ): wqkvb (dead after QKV GEMM) -> vtb @0, qatt @1SZ, katt @2SZ
  //   [3SZ): xbf (dead after QKV GEMM) -> wob
  //   [4SZ): qraw (dead after mid -> aout)
  //   [5SZ): kraw
  //   [6SZ): vraw
  //   [7SZ): lamb
  unsigned short* wqkvb = (unsigned short*)(ws);
  unsigned short* vtb   = (unsigned short*)(ws);           // after QKV GEMM
  unsigned short* qatt  = (unsigned short*)(ws + SZ);      // after QKV GEMM
  unsigned short* katt  = (unsigned short*)(ws + 2 * SZ);  // after QKV GEMM
  unsigned short* xbf   = (unsigned short*)(ws + 3 * SZ);
  unsigned short* wob   = xbf;                             // after QKV GEMM
  unsigned short* qraw  = (unsigned short*)(ws + 4 * SZ);
  unsigned short* kraw  = (unsigned short*)(ws + 5 * SZ);
  unsigned short* vraw  = (unsigned short*)(ws + 6 * SZ);
  unsigned short* aout  = qraw;  // after mid
  float* lamb           = (float*)(ws + 7 * SZ);

  const int N4 = 2048 * 2048 / 4;
  // cvt x/wq/wk/wv (grid.y 0..3) + lambda (grid.y 4, block 0)
  pre_kernel<<<dim3(N4 / 256, 5), 256, 0, stream>>>(
      x, wq, wk, wv, xbf, wqkvb, wqkvb + (size_t)2048 * 2048,
      wqkvb + (size_t)2 * 2048 * 2048, lq1, lq2, lk1, lk2, lamb, N4);

  // fused QKV projection: M=2048, N=6144 (q|k|v contiguous), K=2048, plain epilogue
  gemm_bk64<unsigned short><<<dim3(16, 48), 256, 0, stream>>>(xbf, wqkvb, qraw,
                                                              2048, 2048, 2048);

  // rope(q) + rope(k,rel) + cvt(wo)->wob + transpose(V)->vtb, one launch
  mid_kernel<<<2 * ROPE_BLKS + CVT_BLKS + TRN_BLKS, 256, 0, stream>>>(
      qraw, kraw, vraw, rel, wo, qatt, katt, wob, vtb);

  attn_mfma<<<dim3(512), 256, 0, stream>>>(qatt, katt, vtb, lamb, subw, aout);

  gemm_bk64<float><<<dim3(16, 16), 256, 0, stream>>>(aout, wob, out, 2048, 2048, 2048);
}

// Round 20
// 186.450 us; speedup vs baseline: 1.2936x; 1.2936x over previous
//
#include <hip/hip_runtime.h>

typedef __bf16 bf16x8 __attribute__((ext_vector_type(8)));
typedef float f32x4 __attribute__((ext_vector_type(4)));

__device__ __forceinline__ float bf2f(unsigned short u) {
  return __uint_as_float(((unsigned)u) << 16);
}
__device__ __forceinline__ unsigned short f2bf(float f) {
  unsigned u = __float_as_uint(f);
  return (unsigned short)((u + 0x7fffu + ((u >> 16) & 1u)) >> 16);
}
__device__ __forceinline__ unsigned pack2(float a, float b) {
  return (unsigned)f2bf(a) | ((unsigned)f2bf(b) << 16);
}

// XOR swizzle on 16B blocks within a 128B row (T2 / Guideline 4).
#define SWZB(row, byte) ((byte) ^ (((row) & 7) << 4))

#define AS_GLOBAL(p) ((const __attribute__((address_space(1))) void*)(p))
#define AS_LDS(p) ((__attribute__((address_space(3))) void*)(p))

// ---------------- pre: 4x fp32->bf16 cvt + lambda scalar (grid.y==4) ----------------
__global__ __launch_bounds__(256) void pre_kernel(
    const float* __restrict__ s0, const float* __restrict__ s1,
    const float* __restrict__ s2, const float* __restrict__ s3,
    unsigned short* __restrict__ d0, unsigned short* __restrict__ d1,
    unsigned short* __restrict__ d2, unsigned short* __restrict__ d3,
    const float* __restrict__ lq1, const float* __restrict__ lq2,
    const float* __restrict__ lk1, const float* __restrict__ lk2,
    float* __restrict__ lamb, int n4) {
  if (blockIdx.y == 4) {
    if (blockIdx.x == 0 && threadIdx.x < 64) {
      int l = threadIdx.x;
      float p1 = lq1[l] * lk1[l];
      float p2 = lq2[l] * lk2[l];
      #pragma unroll
      for (int off = 32; off; off >>= 1) {
        p1 += __shfl_xor(p1, off);
        p2 += __shfl_xor(p2, off);
      }
      if (l == 0) lamb[0] = expf(p1) - expf(p2) + 0.7836057665316245f;  // LAMBDA_INIT
    }
    return;
  }
  int idx = blockIdx.x * 256 + threadIdx.x;
  if (idx >= n4) return;
  const float* s;
  unsigned short* d;
  switch (blockIdx.y) {
    case 0: s = s0; d = d0; break;
    case 1: s = s1; d = d1; break;
    case 2: s = s2; d = d2; break;
    default: s = s3; d = d3; break;
  }
  float4 v = reinterpret_cast<const float4*>(s)[idx];
  uint2 pk;
  pk.x = pack2(v.x, v.y);
  pk.y = pack2(v.z, v.w);
  reinterpret_cast<uint2*>(d)[idx] = pk;
}

// ---------------- GEMM (bf16 x bf16), BK=64, swizzled global_load_lds ----------------
// Single-buffer 1-phase: 32 KB LDS -> 3 blocks/CU; inter-block wave overlap (m114)
// hides the stage drain better than intra-block dbuf (R13 A/B). PLAIN store epilogue
// only (R11). No setprio (m190). R19: flat grid + T1 XCD decode - same-bn blocks land
// on one XCD (B-panel 512KB x cols_per_xcd <= L2), mapping HW-confirmed in R8.
// Grid: flat N = 16 * NBCOLS blocks, NBCOLS % 8 == 0.
template <typename OT>
__global__ __launch_bounds__(256)
void gemm_bk64(const unsigned short* __restrict__ A, const unsigned short* __restrict__ Bw,
               OT* __restrict__ C, int M, int K, int ldc) {
  const int nb = blockIdx.x;
  const int xcd = nb & 7, idx = nb >> 3;
  const int cpx = gridDim.x >> 7;  // cols per XCD = (grid/8)/16
  const int bm = (idx & 15) * 128;
  const int bn = (xcd * cpx + (idx >> 4)) * 128;

  __shared__ __align__(16) unsigned short As[128 * 64];
  __shared__ __align__(16) unsigned short Bs[128 * 64];
  const int tid = threadIdx.x;
  const int lane = tid & 63, wave = tid >> 6;
  const int wm = (wave >> 1) * 64, wn = (wave & 1) * 64;
  const int rr = lane & 15, lg = lane >> 4;
  const int srow = lane >> 3;           // row within 8-row slab
  const int sblk = (lane & 7) ^ srow;   // pre-swizzled 16B block
  const char* ab = reinterpret_cast<const char*>(As);
  const char* bb = reinterpret_cast<const char*>(Bs);
  OT* Cb = C + (size_t)(bn / ldc) * ((size_t)M * ldc) + (bn % ldc);
  f32x4 acc[4][4] = {};
  for (int kt = 0; kt < K; kt += 64) {
    __syncthreads();
    #pragma unroll
    for (int j = 0; j < 4; ++j) {
      int s = wave + j * 4;  // slab 0..15 (8 rows x 128 B each)
      const unsigned short* asrc = &A[(long)(bm + s * 8 + srow) * K + kt + sblk * 8];
      __builtin_amdgcn_global_load_lds(AS_GLOBAL(asrc), AS_LDS(&As[s * 512]), 16, 0, 0);
      const unsigned short* bsrc = &Bw[(long)(bn + s * 8 + srow) * K + kt + sblk * 8];
      __builtin_amdgcn_global_load_lds(AS_GLOBAL(bsrc), AS_LDS(&Bs[s * 512]), 16, 0, 0);
    }
    __syncthreads();  // vmcnt(0) drain
    bf16x8 af[4][2], bq[4][2];
    #pragma unroll
    for (int i = 0; i < 4; ++i) {
      int row = wm + i * 16 + rr;
      af[i][0] = *reinterpret_cast<const bf16x8*>(ab + row * 128 + SWZB(row, lg * 16));
      af[i][1] = *reinterpret_cast<const bf16x8*>(ab + row * 128 + SWZB(row, 64 + lg * 16));
    }
    #pragma unroll
    for (int j = 0; j < 4; ++j) {
      int row = wn + j * 16 + rr;
      bq[j][0] = *reinterpret_cast<const bf16x8*>(bb + row * 128 + SWZB(row, lg * 16));
      bq[j][1] = *reinterpret_cast<const bf16x8*>(bb + row * 128 + SWZB(row, 64 + lg * 16));
    }
    #pragma unroll
    for (int i = 0; i < 4; ++i)
      #pragma unroll
      for (int j = 0; j < 4; ++j) {
        acc[i][j] = __builtin_amdgcn_mfma_f32_16x16x32_bf16(af[i][0], bq[j][0], acc[i][j], 0, 0, 0);
        acc[i][j] = __builtin_amdgcn_mfma_f32_16x16x32_bf16(af[i][1], bq[j][1], acc[i][j], 0, 0, 0);
      }
  }
  const int cc = lane & 15;
  #pragma unroll
  for (int i = 0; i < 4; ++i)
    #pragma unroll
    for (int j = 0; j < 4; ++j)
      #pragma unroll
      for (int r = 0; r < 4; ++r) {
        long row = bm + wm + i * 16 + lg * 4 + r;
        long col = wn + j * 16 + cc;
        float v = acc[i][j][r];
        if constexpr (sizeof(OT) == 2) Cb[row * ldc + col] = f2bf(v);
        else                           Cb[row * ldc + col] = v;
      }
}

// ---------------- mid: rope(q) + rope(k,rel) + cvt(wo) + transpose(V), one launch ------
#define ROPE_BLKS 8192
#define CVT_BLKS 4096
#define TRN_BLKS 1024
__global__ __launch_bounds__(256) void mid_kernel(
    const unsigned short* __restrict__ qraw, const unsigned short* __restrict__ kraw,
    const unsigned short* __restrict__ vraw, const float* __restrict__ rel,
    const float* __restrict__ wo,
    unsigned short* __restrict__ qatt, unsigned short* __restrict__ katt,
    unsigned short* __restrict__ wob, unsigned short* __restrict__ vtb) {
  __shared__ unsigned short ls[64][68];
  const int bid = blockIdx.x;
  const int tid = threadIdx.x;
  if (bid < 2 * ROPE_BLKS) {
    const int use_rel = bid >= ROPE_BLKS;
    const unsigned short* raw = use_rel ? kraw : qraw;
    unsigned short* outp = use_rel ? katt : qatt;
    int idx = (bid & (ROPE_BLKS - 1)) * 256 + tid;
    int i = idx & 31;
    int t = (idx >> 5) & 1023;
    int hp = (idx >> 15) & 31;
    int b = idx >> 20;
    int src = (b * 1024 + t) * 2048 + hp * 64 + 2 * i;
    unsigned pair = *reinterpret_cast<const unsigned*>(&raw[src]);
    float x1 = __uint_as_float(pair << 16);
    float x2 = __uint_as_float(pair & 0xffff0000u);
    if (use_rel) {
      x1 *= rel[t * 64 + 2 * i];
      x2 *= rel[t * 64 + 2 * i + 1];
    }
    float inv = expf(-0.28782313662425574f * (float)i);  // 10000^(-2i/64)
    float s, c;
    sincosf((float)t * inv, &s, &c);
    int dst = ((b * 32 + hp) * 1024 + t) * 64 + 2 * i;
    *reinterpret_cast<unsigned*>(&outp[dst]) = pack2(x1 * c - x2 * s, x1 * s + x2 * c);
  } else if (bid < 2 * ROPE_BLKS + CVT_BLKS) {
    int idx = (bid - 2 * ROPE_BLKS) * 256 + tid;
    float4 v = reinterpret_cast<const float4*>(wo)[idx];
    uint2 pk;
    pk.x = pack2(v.x, v.y);
    pk.y = pack2(v.z, v.w);
    reinterpret_cast<uint2*>(wob)[idx] = pk;
  } else {
    int tb = bid - (2 * ROPE_BLKS + CVT_BLKS);
    const int t0 = (tb & 15) * 64, n0 = ((tb >> 4) & 31) * 64, b = tb >> 9;
    #pragma unroll
    for (int p = 0; p < 4; ++p) {
      int idx = p * 256 + tid;
      int tl = idx >> 4, nq = (idx & 15) * 4;
      *reinterpret_cast<uint2*>(&ls[tl][nq]) = *reinterpret_cast<const uint2*>(
          &vraw[((long)(b * 1024 + t0 + tl)) * 2048 + n0 + nq]);
    }
    __syncthreads();
    #pragma unroll
    for (int p = 0; p < 4; ++p) {
      int idx = p * 256 + tid;
      int nl = idx >> 4, tq = (idx & 15) * 4;
      uint2 o;
      o.x = (unsigned)ls[tq + 0][nl] | ((unsigned)ls[tq + 1][nl] << 16);
      o.y = (unsigned)ls[tq + 2][nl] | ((unsigned)ls[tq + 3][nl] << 16);
      *reinterpret_cast<uint2*>(&vtb[((long)(b * 2048 + n0 + nl)) * 1024 + t0 + tq]) = o;
    }
  }
}

// ---------------- MFMA differential flash attention + fused sub-LN ----------------
// R15 version restored (session best): balanced 2-pass blocks, T1 XCD decode,
// gload_lds DOUBLE-buffered K/V (R19 lesson: staging's value is latency decoupling -
// direct-global frag loads put ~200cy L2 latency in every MFMA chain, attn 50->108us).
// No setprio (m190). No min-waves bound (R16: forced VGPR=64 -> acc spill).
__global__ __launch_bounds__(256) void attn_mfma(
    const unsigned short* __restrict__ Qa,   // (B,32,T,64) bf16
    const unsigned short* __restrict__ Ka,   // (B,32,T,64) bf16
    const unsigned short* __restrict__ Vt,   // (B,2048,T) bf16 (V transposed)
    const float* __restrict__ lam_p,
    const float* __restrict__ subln,         // 128
    unsigned short* __restrict__ O) {        // (B,T,2048) bf16
  const int n = blockIdx.x;
  const int c = n & 7, m = n >> 3;
  const int g = c * 4 + (m >> 4);  // 0..31
  const int bx = m & 15;
  const int h = g & 15, b = g >> 4;

  const int tid = threadIdx.x;
  const int lane = tid & 63, w = tid >> 6;
  const int lg = lane >> 4, cc = lane & 15;
  const int hh = w >> 1, qoff = (w & 1) * 16;

  __shared__ __align__(16) unsigned short KsBuf[2][2 * 64 * 64];  // 2 x 16 KB
  __shared__ __align__(16) unsigned short VsBuf[2][128 * 64];     // 2 x 16 KB
  __shared__ __align__(16) unsigned short PbBuf[4 * 16 * 64];     // 8 KB, per-wave P

  const float lam = lam_p[0];
  char* ksb0 = reinterpret_cast<char*>(&KsBuf[0][0]);
  char* vsb0 = reinterpret_cast<char*>(&VsBuf[0][0]);
  char* pbb = reinterpret_cast<char*>(PbBuf) + w * 2048;
  float* cb = reinterpret_cast<float*>(&KsBuf[0][0]);

  const int srow = lane >> 3;
  const int sblk = (lane & 7) ^ srow;
  auto STAGE = [&](char* kd, char* vd, int k0) {
    #pragma unroll
    for (int j = 0; j < 4; ++j) {
      int s = w * 4 + j;  // 0..15
      int sh = s >> 3, rg = s & 7;
      const unsigned short* ksrc =
          &Ka[(((long)(b * 32 + 2 * h + sh)) * 1024 + k0 + rg * 8 + srow) * 64 + sblk * 8];
      __builtin_amdgcn_global_load_lds(AS_GLOBAL(ksrc), AS_LDS(kd + sh * 8192 + rg * 1024),
                                       16, 0, 0);
      const unsigned short* vsrc =
          &Vt[((long)(b * 2048 + h * 128 + s * 8 + srow)) * 1024 + k0 + sblk * 8];
      __builtin_amdgcn_global_load_lds(AS_GLOBAL(vsrc), AS_LDS(vd + s * 1024), 16, 0, 0);
    }
  };

  float sl[8];
  #pragma unroll
  for (int jc = 0; jc < 8; ++jc) sl[jc] = subln[jc * 16 + cc];

  const long kbase = (long)((b * 32 + 2 * h + hh) * 1024);

  for (int pass = 0; pass < 2; ++pass) {
    const int q0 = (pass ? (31 - bx) : bx) * 32;
    const int nt = ((q0 + 31) >> 6) + 1;

    __syncthreads();
    STAGE(ksb0, vsb0, 0);

    bf16x8 qf[2];
    {
      const long qrow = q0 + qoff + cc;
      #pragma unroll
      for (int c2 = 0; c2 < 2; ++c2)
        qf[c2] = *reinterpret_cast<const bf16x8*>(&Qa[(kbase + qrow) * 64 + c2 * 32 + lg * 8]);
    }
    f32x4 acc_o[8];
    float mS[4], lS[4];
    #pragma unroll
    for (int jc = 0; jc < 8; ++jc) acc_o[jc] = (f32x4){0.f, 0.f, 0.f, 0.f};
    #pragma unroll
    for (int r = 0; r < 4; ++r) { mS[r] = -1e30f; lS[r] = 0.f; }

    __syncthreads();

    int cur = 0;
    for (int tile = 0; tile < nt; ++tile) {
      if (tile + 1 < nt)
        STAGE(ksb0 + (cur ^ 1) * 16384, vsb0 + (cur ^ 1) * 16384, (tile + 1) * 64);
      char* kb = ksb0 + cur * 16384;
      char* vb = vsb0 + cur * 16384;

      const int k0 = tile * 64;
      f32x4 s4[4];
      #pragma unroll
      for (int j = 0; j < 4; ++j) s4[j] = (f32x4){0.f, 0.f, 0.f, 0.f};
      #pragma unroll
      for (int j = 0; j < 4; ++j) {
        int row = j * 16 + cc;
        const char* base = kb + hh * 8192 + row * 128;
        bf16x8 kb0 = *reinterpret_cast<const bf16x8*>(base + SWZB(row, lg * 16));
        bf16x8 kb1 = *reinterpret_cast<const bf16x8*>(base + SWZB(row, lg * 16 + 64));
        s4[j] = __builtin_amdgcn_mfma_f32_16x16x32_bf16(qf[0], kb0, s4[j], 0, 0, 0);
        s4[j] = __builtin_amdgcn_mfma_f32_16x16x32_bf16(qf[1], kb1, s4[j], 0, 0, 0);
      }
      #pragma unroll
      for (int j = 0; j < 4; ++j) {
        int kcol = k0 + j * 16 + cc;
        #pragma unroll
        for (int r = 0; r < 4; ++r) {
          int qrow = q0 + qoff + lg * 4 + r;
          float s = s4[j][r] * 0.125f;
          s4[j][r] = (kcol > qrow) ? -1e30f : s;
        }
      }
      float rescv[4];
      #pragma unroll
      for (int r = 0; r < 4; ++r) {
        float mx = fmaxf(fmaxf(s4[0][r], s4[1][r]), fmaxf(s4[2][r], s4[3][r]));
        mx = fmaxf(mx, __shfl_xor(mx, 1));
        mx = fmaxf(mx, __shfl_xor(mx, 2));
        mx = fmaxf(mx, __shfl_xor(mx, 4));
        mx = fmaxf(mx, __shfl_xor(mx, 8));
        float mold = mS[r];
        float mnew = fmaxf(mold, mx);
        mS[r] = mnew;
        float rsc = __expf(mold - mnew);
        rescv[r] = rsc;
        float ls = 0.f;
        #pragma unroll
        for (int j = 0; j < 4; ++j) {
          float p = __expf(s4[j][r] - mnew);
          s4[j][r] = p;
          ls += p;
        }
        ls += __shfl_xor(ls, 1);
        ls += __shfl_xor(ls, 2);
        ls += __shfl_xor(ls, 4);
        ls += __shfl_xor(ls, 8);
        lS[r] = lS[r] * rsc + ls;
      }
      #pragma unroll
      for (int j = 0; j < 4; ++j)
        #pragma unroll
        for (int r = 0; r < 4; ++r) {
          int rowl = lg * 4 + r;
          *reinterpret_cast<unsigned short*>(
              pbb + rowl * 128 + SWZB(rowl, (j * 16 + cc) * 2)) = f2bf(s4[j][r]);
        }

      bf16x8 pa[2];
      #pragma unroll
      for (int c2 = 0; c2 < 2; ++c2)
        pa[c2] = *reinterpret_cast<const bf16x8*>(pbb + cc * 128 + SWZB(cc, lg * 16 + c2 * 64));
      #pragma unroll
      for (int jc = 0; jc < 8; ++jc)
        #pragma unroll
        for (int r = 0; r < 4; ++r)
          acc_o[jc][r] *= rescv[r];
      #pragma unroll
      for (int jc = 0; jc < 8; ++jc) {
        int row = jc * 16 + cc;
        const char* base = vb + row * 128;
        bf16x8 vf0 = *reinterpret_cast<const bf16x8*>(base + SWZB(row, lg * 16));
        bf16x8 vf1 = *reinterpret_cast<const bf16x8*>(base + SWZB(row, lg * 16 + 64));
        acc_o[jc] = __builtin_amdgcn_mfma_f32_16x16x32_bf16(pa[0], vf0, acc_o[jc], 0, 0, 0);
        acc_o[jc] = __builtin_amdgcn_mfma_f32_16x16x32_bf16(pa[1], vf1, acc_o[jc], 0, 0, 0);
      }

      __syncthreads();
      cur ^= 1;
    }

    if (hh == 1) {
      #pragma unroll
      for (int r = 0; r < 4; ++r) {
        float inv2 = lam / lS[r];
        int row = qoff + lg * 4 + r;
        #pragma unroll
        for (int jc = 0; jc < 8; ++jc)
          cb[row * 128 + ((jc ^ (row & 7)) * 16 + cc)] = acc_o[jc][r] * inv2;
      }
    }
    __syncthreads();
    if (hh == 0) {
      float sc[4];
      #pragma unroll
      for (int r = 0; r < 4; ++r) {
        float inv1 = 1.f / lS[r];
        int row = qoff + lg * 4 + r;
        float ss = 0.f;
        #pragma unroll
        for (int jc = 0; jc < 8; ++jc) {
          float at = acc_o[jc][r] * inv1 - cb[row * 128 + ((jc ^ (row & 7)) * 16 + cc)];
          acc_o[jc][r] = at;
          ss += at * at;
        }
        ss += __shfl_xor(ss, 1);
        ss += __shfl_xor(ss, 2);
        ss += __shfl_xor(ss, 4);
        ss += __shfl_xor(ss, 8);
        sc[r] = rsqrtf(ss * (1.f / 128.f) + 1e-5f);
      }
      #pragma unroll
      for (int r = 0; r < 4; ++r) {
        long qrow = q0 + qoff + lg * 4 + r;
        #pragma unroll
        for (int jc = 0; jc < 8; ++jc) {
          O[(long)(b * 1024 + qrow) * 2048 + h * 128 + jc * 16 + cc] =
              f2bf(acc_o[jc][r] * sc[r] * sl[jc]);
        }
      }
    }
  }
}

extern "C" void kernel_launch(void* const* d_in, const int* in_sizes, int n_in,
                              void* d_out, int out_size, void* d_ws, size_t ws_size,
                              hipStream_t stream) {
  (void)in_sizes; (void)n_in; (void)out_size; (void)ws_size;
  const float* x    = (const float*)d_in[0];
  const float* rel  = (const float*)d_in[1];
  const float* wq   = (const float*)d_in[2];
  const float* wk   = (const float*)d_in[3];
  const float* wv   = (const float*)d_in[4];
  const float* lq1  = (const float*)d_in[5];
  const float* lq2  = (const float*)d_in[6];
  const float* lk1  = (const float*)d_in[7];
  const float* lk2  = (const float*)d_in[8];
  const float* subw = (const float*)d_in[9];
  const float* wo   = (const float*)d_in[10];
  float* out = (float*)d_out;

  char* ws = (char*)d_ws;
  const size_t SZ = (size_t)2048 * 2048 * 2;  // 8 MB
  // Liveness-ordered layout (56 MB + 4 B):
  //   [0..3SZ): wqkvb (dead after QKV GEMM) -> vtb @0, qatt @1SZ, katt @2SZ
  //   [3SZ): xbf (dead after QKV GEMM) -> wob
  //   [4SZ): qraw (dead after mid -> aout)
  //   [5SZ): kraw   [6SZ): vraw   [7SZ): lamb
  unsigned short* wqkvb = (unsigned short*)(ws);
  unsigned short* vtb   = (unsigned short*)(ws);           // after QKV GEMM
  unsigned short* qatt  = (unsigned short*)(ws + SZ);      // after QKV GEMM
  unsigned short* katt  = (unsigned short*)(ws + 2 * SZ);  // after QKV GEMM
  unsigned short* xbf   = (unsigned short*)(ws + 3 * SZ);
  unsigned short* wob   = xbf;                             // after QKV GEMM
  unsigned short* qraw  = (unsigned short*)(ws + 4 * SZ);
  unsigned short* kraw  = (unsigned short*)(ws + 5 * SZ);
  unsigned short* vraw  = (unsigned short*)(ws + 6 * SZ);
  unsigned short* aout  = qraw;  // after mid
  float* lamb           = (float*)(ws + 7 * SZ);

  const int N4 = 2048 * 2048 / 4;
  // cvt x/wq/wk/wv (grid.y 0..3) + lambda (grid.y 4, block 0)
  pre_kernel<<<dim3(N4 / 256, 5), 256, 0, stream>>>(
      x, wq, wk, wv, xbf, wqkvb, wqkvb + (size_t)2048 * 2048,
      wqkvb + (size_t)2 * 2048 * 2048, lq1, lq2, lk1, lk2, lamb, N4);

  // fused QKV projection: M=2048, N=6144, K=2048; flat grid + XCD decode (48 cols)
  gemm_bk64<unsigned short><<<dim3(768), 256, 0, stream>>>(xbf, wqkvb, qraw,
                                                           2048, 2048, 2048);

  // rope(q) + rope(k,rel) + cvt(wo)->wob + transpose(V)->vtb, one launch
  mid_kernel<<<2 * ROPE_BLKS + CVT_BLKS + TRN_BLKS, 256, 0, stream>>>(
      qraw, kraw, vraw, rel, wo, qatt, katt, wob, vtb);

  attn_mfma<<<dim3(512), 256, 0, stream>>>(qatt, katt, vtb, lamb, subw, aout);

  // out projection: 16 cols -> flat grid 256 + XCD decode
  gemm_bk64<float><<<dim3(256), 256, 0, stream>>>(aout, wob, out, 2048, 2048, 2048);
}